// Round 1
// baseline (1908.860 us; speedup 1.0000x reference)
//
#include <hip/hip_runtime.h>

// Decoder GRU, B=128 T=512 X=64 H=256, skip=4 (runtime, 1..7; skip==0 uses
// slow generic path).  Round 7: single-barrier fused step.
//
// R6 counters: VALUBusy 16%, HBM 0.2%, 8000 cyc/step vs ~1100 cyc of issue
// -> barrier/serialization bound (4 barriers/step, partial-sum LDS round
// trips, narrow finalize phases).  For i >= 2*skip the projection input
// pt(i) = h(i-1) + h(i-2*skip) is independent of step i's gates, so it is
// produced at step i-1 and each step collapses to ONE phase + ONE barrier:
//   - thread (c=t>>1, kh=t&1): gate k-half partials -> shfl_xor(1) reduce
//     (replaces part[] LDS + barrier); both lanes finalize r/z/n.
//   - same threads as (xc=t>>3, sl=t&7): projection partials -> shfl_xor
//     (1,2,4) reduce (replaces pp[] LDS + barrier); runs concurrently with
//     the gate dot chains (independent -> ILP).
//   - hid2/pt2/xt2 double-buffered by step parity; single barrier ends step.
// First 2*skip steps use a generic 2-barrier prologue (placeholder edges).
// Weights: W_hh+W_ih fp16 in registers (as R6, ~240 regs); W_out fp16 in LDS
// [j][t] layout (per-lane consecutive 16B -> conflict-free ds_read_b128).
typedef _Float16 h2_t __attribute__((ext_vector_type(2)));

constexpr int T_ = 512;
constexpr int X_ = 64;
constexpr int H_ = 256;
constexpr int NWG = 128;  // 1 batch per WG
constexpr int NT = 512;   // 8 waves; >=129 VGPR forces 1 WG/CU
constexpr int RS = 16;    // ring slots; lookback 2*skip, OK for skip <= 7

// fp16 weight images in d_ws (uint4 units)
constexpr int GHH_U4 = 3 * 2 * 16 * 256;  // [g][kh][j][c]
constexpr int GIH_U4 = 3 * 2 * 4 * 256;   // [g][kh][j][c]
constexpr int GOUT_U4 = 2048;             // [j][t]  (t = xc*8+sl)
constexpr int G_TOTAL = GHH_U4 + GIH_U4 + GOUT_U4;

__device__ __forceinline__ float sigmoid_f(float x) {
  float e = __expf(fminf(-x, 80.f));
  return 1.f / (1.f + e);
}
__device__ __forceinline__ float tanh_f(float x) {
  float e = __expf(fminf(-2.f * x, 80.f));
  return (1.f - e) / (1.f + e);
}

__device__ __forceinline__ unsigned pk2(float a, float b) {
  h2_t v;
  v[0] = (_Float16)a;
  v[1] = (_Float16)b;
  return __builtin_bit_cast(unsigned, v);
}
__device__ __forceinline__ uint4 pk8(const float* s) {
  return make_uint4(pk2(s[0], s[1]), pk2(s[2], s[3]), pk2(s[4], s[5]),
                    pk2(s[6], s[7]));
}

// fp16-pair dot with fp32 accumulate (v_dot2_f32_f16)
__device__ __forceinline__ float dotp(unsigned w, unsigned h, float acc) {
  h2_t wv = __builtin_bit_cast(h2_t, w);
  h2_t hv = __builtin_bit_cast(h2_t, h);
#if __has_builtin(__builtin_amdgcn_fdot2)
  return __builtin_amdgcn_fdot2(wv, hv, acc, false);
#else
  acc = fmaf((float)wv[0], (float)hv[0], acc);
  return fmaf((float)wv[1], (float)hv[1], acc);
#endif
}
__device__ __forceinline__ float dotq(uint4 w, uint4 h, float acc) {
  acc = dotp(w.x, h.x, acc);
  acc = dotp(w.y, h.y, acc);
  acc = dotp(w.z, h.z, acc);
  acc = dotp(w.w, h.w, acc);
  return acc;
}

// One-time fp32 -> fp16 pack + transpose into register/LDS-friendly layouts.
__global__ void prep_kernel(const float* __restrict__ Wih,
                            const float* __restrict__ Whh,
                            const float* __restrict__ Wout,
                            uint4* __restrict__ G) {
  int id = blockIdx.x * 256 + threadIdx.x;
  if (id < GHH_U4) {
    int c = id & 255, r = id >> 8;
    int j = r & 15, gk = r >> 4, g = gk >> 1, kh = gk & 1;
    G[id] = pk8(Whh + (size_t)(g * 256 + c) * H_ + kh * 128 + j * 8);
  } else if (id < GHH_U4 + GIH_U4) {
    int jd = id - GHH_U4;
    int c = jd & 255, r = jd >> 8;
    int j = r & 3, gk = r >> 2, g = gk >> 1, kh = gk & 1;
    G[id] = pk8(Wih + (size_t)(g * 256 + c) * X_ + kh * 32 + j * 8);
  } else if (id < G_TOTAL) {
    int jd = id - GHH_U4 - GIH_U4;  // [0,2048): [j][t]
    int j = jd >> 9, tt = jd & 511;
    int xcp = tt >> 3, sl = tt & 7;
    G[id] = pk8(Wout + (size_t)xcp * H_ + sl * 32 + j * 8);
  }
}

// ---- per-step building blocks (p/q are compile-time 0/1 in the main loop) --

#define GATES(p, i, hn)                                                      \
  float hn;                                                                  \
  {                                                                          \
    float a0 = 0, a1 = 0, z0 = 0, z1 = 0, n0 = 0, n1 = 0, ni = 0;            \
    const uint4* h4 = ((const uint4*)hid2[p]) + kh * 16;                     \
    _Pragma("unroll") for (int j = 0; j < 16; j += 2) {                      \
      uint4 ha = h4[j], hb = h4[j + 1];                                      \
      a0 = dotq(whh[j], ha, a0);                                             \
      a1 = dotq(whh[j + 1], hb, a1);                                         \
      z0 = dotq(whh[16 + j], ha, z0);                                        \
      z1 = dotq(whh[17 + j], hb, z1);                                        \
      n0 = dotq(whh[32 + j], ha, n0);                                        \
      n1 = dotq(whh[33 + j], hb, n1);                                        \
    }                                                                        \
    const uint4* x4 = ((const uint4*)xt2[p]) + kh * 4;                       \
    _Pragma("unroll") for (int j = 0; j < 4; ++j) {                          \
      uint4 x8 = x4[j];                                                      \
      a0 = dotq(wih[j], x8, a0);                                             \
      z0 = dotq(wih[4 + j], x8, z0);                                         \
      ni = dotq(wih[8 + j], x8, ni);                                         \
    }                                                                        \
    float ar = a0 + a1, az = z0 + z1, anh = n0 + n1;                         \
    ar += __shfl_xor(ar, 1);                                                 \
    az += __shfl_xor(az, 1);                                                 \
    anh += __shfl_xor(anh, 1);                                               \
    ni += __shfl_xor(ni, 1);                                                 \
    float r = sigmoid_f(ar + bsr);                                           \
    float z = sigmoid_f(az + bsz);                                           \
    float n = tanh_f(ni + bin_ + r * (anh + bhn_));                          \
    hn = fmaf(z, hid_reg - n, n); /* (1-z)*n + z*hidden */                   \
    if (kh == 0) ring[(i) & (RS - 1)][c] = hn;                               \
  }

#define PROJ(p, q, i)                                                        \
  {                                                                          \
    float fa = 0;                                                            \
    const uint4* pp4 = (const uint4*)pt2[p];                                 \
    _Pragma("unroll") for (int j = 0; j < 4; ++j) fa =                       \
        dotq(wout_r[j * NT + t], pp4[sl * 4 + j], fa);                       \
    fa += __shfl_xor(fa, 1);                                                 \
    fa += __shfl_xor(fa, 2);                                                 \
    fa += __shfl_xor(fa, 4);                                                 \
    float o = fa + bo;                                                       \
    if (sl == 0) out[ob + (size_t)(i)*X_ + xc] = o;                          \
    float oo = __shfl_xor(o, 8);                                             \
    if ((t & 15) == 0) xt2[q][t >> 4] = pk2(o, oo);                          \
  }

// Main-loop step (valid for i >= 2*skip, skip >= 1): pt2[p] was produced at
// step i-1; sg == sp == h(i+1-2*skip) for the next step's hidden/pt.
#define MSTEP(i, p, q)                                                       \
  {                                                                          \
    GATES(p, i, hn)                                                          \
    PROJ(p, q, i)                                                            \
    if ((i) + 1 < T_) {                                                      \
      float sgp = ring[((i) + 1 - 2 * skip) & (RS - 1)][c];                  \
      float hidn = m0f[(i) + 1] * hn + m1f[(i) + 1] * sgp;                   \
      float ptn = hn + sgp;                                                  \
      hid_reg = hidn;                                                        \
      float ho = __shfl_xor(hidn, 2);                                        \
      float po = __shfl_xor(ptn, 2);                                         \
      if ((t & 3) == 0) {                                                    \
        hid2[q][t >> 2] = pk2(hidn, ho);                                     \
        pt2[q][t >> 2] = pk2(ptn, po);                                       \
      }                                                                      \
    }                                                                        \
    __syncthreads();                                                         \
  }

__global__ __launch_bounds__(NT, 1) void decoder_kernel(
    const float* __restrict__ h_enc, const float* __restrict__ b_ih,
    const float* __restrict__ b_hh, const float* __restrict__ b_out,
    const int* __restrict__ mask0, const int* __restrict__ mask1,
    const int* __restrict__ skipp, const uint4* __restrict__ G,
    float* __restrict__ out) {
  __shared__ float ring[RS][H_];                   // 16 KB h history
  __shared__ alignas(16) unsigned hid2[2][H_ / 2]; // hidden, fp16 pairs
  __shared__ alignas(16) unsigned pt2[2][H_ / 2];  // h_prev+skip_p pairs
  __shared__ alignas(16) unsigned xt2[2][X_ / 2];  // x feedback pairs
  __shared__ alignas(16) uint4 wout_r[4 * NT];     // 32 KB W_out fp16 [j][t]
  __shared__ float m0f[T_], m1f[T_];               // 4 KB masks

  const int t = threadIdx.x;
  const int b = blockIdx.x;
  const int c = t >> 1, kh = t & 1;  // gate role
  const int xc = t >> 3, sl = t & 7; // projection role
  const size_t ob = (size_t)b * T_ * X_;

  // ---- persistent weight registers (fp16 pairs) ----
  uint4 whh[48];  // 3 gates x 16 uint4 (128 k each)
  uint4 wih[12];  // 3 gates x 4 uint4 (32 k each)
#pragma unroll
  for (int u = 0; u < 48; ++u)
    whh[u] = G[((u >> 4) * 32 + kh * 16 + (u & 15)) * 256 + c];
#pragma unroll
  for (int u = 0; u < 12; ++u)
    wih[u] = G[GHH_U4 + ((u >> 2) * 8 + kh * 4 + (u & 3)) * 256 + c];
#pragma unroll
  for (int j = 0; j < 4; ++j)
    wout_r[t + NT * j] = G[GHH_U4 + GIH_U4 + t + NT * j];
  m0f[t] = (float)mask0[t];
  m1f[t] = (float)mask1[t];

  const int skip = skipp[0];
  const int i0 = (skip == 0) ? T_ : ((2 * skip < T_) ? 2 * skip : T_);

  const float bsr = b_ih[c] + b_hh[c];
  const float bsz = b_ih[H_ + c] + b_hh[H_ + c];
  const float bin_ = b_ih[2 * H_ + c];
  const float bhn_ = b_hh[2 * H_ + c];
  const float bo = b_out[xc];

  float hp = h_enc[(size_t)b * H_ + c];
  float hid_reg = (float)mask0[0] * hp;  // hidden(0); skip_g(0) == 0
  float hps_reg = hp;                    // h_prev(0) = h_enc
  {
    float ho = __shfl_xor(hid_reg, 2);
    if ((t & 3) == 0) hid2[0][t >> 2] = pk2(hid_reg, ho);
  }
  if (t < X_ / 2) xt2[0][t] = 0u;  // GO token
  __syncthreads();

  // ---- prologue: generic 2-barrier steps for i < 2*skip ----
  for (int i = 0; i < i0; ++i) {
    const int p = i & 1, q = p ^ 1;
    GATES(p, i, hn)
    {
      int ppos = (i < skip) ? 2 * i + 1 : i - skip;
      bool pz = ppos < skip;
      int pi = ppos - skip;
      if (pi < 0) pi = 0;
      float sp = pz ? 0.f : ((pi == i) ? hn : ring[pi & (RS - 1)][c]);
      float ptv = hps_reg + sp;
      float po = __shfl_xor(ptv, 2);
      if ((t & 3) == 0) pt2[p][t >> 2] = pk2(ptv, po);
    }
    if (i + 1 < T_) {
      int i1 = i + 1;
      int pg = (i1 < skip) ? 2 * i1 : i1 - skip;
      bool gz = pg < skip;
      int gi = pg - skip;
      if (gi < 0) gi = 0;
      if (gi >= i1) gz = true;  // unwritten slot == reference zero init
      float sg = gz ? 0.f : ((gi == i) ? hn : ring[gi & (RS - 1)][c]);
      float hidn = m0f[i1] * hn + m1f[i1] * sg;
      hid_reg = hidn;
      float ho = __shfl_xor(hidn, 2);
      if ((t & 3) == 0) hid2[q][t >> 2] = pk2(hidn, ho);
      if (skip > 0 && i1 >= 2 * skip) {  // handoff into fused main loop
        float sgp = ring[(i1 - 2 * skip) & (RS - 1)][c];
        float ptn = hn + sgp;
        float po2 = __shfl_xor(ptn, 2);
        if ((t & 3) == 0) pt2[q][t >> 2] = pk2(ptn, po2);
      }
    }
    hps_reg = hn;
    __syncthreads();
    PROJ(p, q, i)
    __syncthreads();
  }

  // ---- main loop: one barrier per step; i0 is even so parity is static ----
#pragma unroll 1
  for (int i = i0; i < T_; i += 2) {
    MSTEP(i, 0, 1)
    MSTEP(i + 1, 1, 0)
  }
}

extern "C" void kernel_launch(void* const* d_in, const int* in_sizes, int n_in,
                              void* d_out, int out_size, void* d_ws,
                              size_t ws_size, hipStream_t stream) {
  (void)in_sizes; (void)n_in; (void)out_size; (void)ws_size;
  // d_in[0] = input [B,T,X] — unused by the reference computation.
  const float* h_enc = (const float*)d_in[1];
  const float* W_ih = (const float*)d_in[2];
  const float* W_hh = (const float*)d_in[3];
  const float* b_ih = (const float*)d_in[4];
  const float* b_hh = (const float*)d_in[5];
  const float* W_out = (const float*)d_in[6];
  const float* b_out = (const float*)d_in[7];
  const int* mask0 = (const int*)d_in[8];
  const int* mask1 = (const int*)d_in[9];
  const int* skipp = (const int*)d_in[10];
  float* out = (float*)d_out;
  uint4* G = (uint4*)d_ws;  // 512 KB fp16 weight images

  prep_kernel<<<dim3(G_TOTAL / 256), dim3(256), 0, stream>>>(W_ih, W_hh,
                                                             W_out, G);
  decoder_kernel<<<dim3(NWG), dim3(NT), 0, stream>>>(
      h_enc, b_ih, b_hh, b_out, mask0, mask1, skipp, G, out);
}